// Round 6
// baseline (163.333 us; speedup 1.0000x reference)
//
#include <hip/hip_runtime.h>
#include <hip/hip_bf16.h>
#include <math.h>

// Model_58488864637193 — algebraic collapse of the 3 stacked linears:
//   Wc = W1 @ (Ws @ Wr)  [32,4],  bc = (b1 @ (Ws@Wr)) + bs@Wr + br  [4]
// Work: 141 GFLOP -> ~1.1 GFLOP, dominated by the ring-121 484->32 tanh layer.
//
// R5 -> R6: SMEM weight streaming stalls on the un-partial-waitable
// lgkmcnt(0) drain (SMEM is out-of-order). Weights now go through VMEM with
// a vgpr-derived (divergence-analysis-opaque) uniform address -> hardware
// broadcast global_load_dwordx4, double-buffered 2 taps deep so vmcnt(N)
// counted waits keep the stream in flight across each 64-cyc FMA block.
// Wave = 8 neurons x ~60 taps (8 waves = 4 octs x 2 tap-halves), 512 thr,
// __launch_bounds__(512,4) -> 2 blocks/CU, 4 waves/SIMD.

#define L_SEQ 4096
#define TL    64    // output rows per stage1 block (= wave width)

// ---------------- precomp1: T[513][4] = [Ws; bs] @ Wr ----------------
__global__ __launch_bounds__(256) void precomp1_kernel(
    const float* __restrict__ Ws, const float* __restrict__ bs,
    const float* __restrict__ Wr, float* __restrict__ T) {
  const int tid  = threadIdx.x;
  const int k    = blockIdx.x * 4 + (tid >> 6);   // wave id = output row
  const int lane = tid & 63;
  if (k >= 513) return;
  const float4* row4 = (const float4*)((k < 512) ? (Ws + (size_t)k * 4096) : bs);
  const float4* Wr4  = (const float4*)Wr;
  float a0 = 0.f, a1 = 0.f, a2 = 0.f, a3 = 0.f;
#pragma unroll 4
  for (int m4 = lane; m4 < 1024; m4 += 64) {
    const float4 rv = row4[m4];
#pragma unroll
    for (int c = 0; c < 4; ++c) {
      const float  xs = ((const float*)&rv)[c];
      const float4 w  = Wr4[m4 * 4 + c];
      a0 = fmaf(xs, w.x, a0); a1 = fmaf(xs, w.y, a1);
      a2 = fmaf(xs, w.z, a2); a3 = fmaf(xs, w.w, a3);
    }
  }
#pragma unroll
  for (int off = 32; off > 0; off >>= 1) {
    a0 += __shfl_xor(a0, off); a1 += __shfl_xor(a1, off);
    a2 += __shfl_xor(a2, off); a3 += __shfl_xor(a3, off);
  }
  if (lane == 0) {
    float4 o; o.x = a0; o.y = a1; o.z = a2; o.w = a3;
    ((float4*)T)[k] = o;
  }
}

// ---------------- precomp2: WcBc[132] = {Wc[32][4] row-major, bc[4]} ----------------
__global__ __launch_bounds__(128) void precomp2_kernel(
    const float* __restrict__ W1, const float* __restrict__ b1,
    const float* __restrict__ br, const float* __restrict__ T,
    float* __restrict__ WcBc) {
  const int i   = blockIdx.x;        // 0..32
  const int t   = threadIdx.x;       // 0..127
  const int j   = t & 3;
  const int seg = t >> 2;            // 0..31
  const float4* v4 = (const float4*)((i < 32) ? (W1 + (size_t)i * 512) : b1);
  const float4* T4 = (const float4*)T;
  float acc = 0.f;
#pragma unroll
  for (int q = 0; q < 4; ++q) {
    const int m4 = seg * 4 + q;
    const float4 vv = v4[m4];
#pragma unroll
    for (int c = 0; c < 4; ++c) {
      const float4 trow = T4[m4 * 4 + c];
      acc = fmaf(((const float*)&vv)[c], ((const float*)&trow)[j], acc);
    }
  }
  __shared__ float red[128];
  red[t] = acc;
  __syncthreads();
#pragma unroll
  for (int s = 64; s >= 4; s >>= 1) {
    if (t < s) red[t] += red[t + s];
    __syncthreads();
  }
  if (t < 4) {
    float r = red[t];
    if (i == 32) r += T[512 * 4 + t] + br[t];
    WcBc[(i < 32 ? i * 4 : 128) + t] = r;
  }
}

// ---------------- stage1: y = tanh(win121(x) @ W0 + b0) @ Wc + bc ----------------
// 512 blocks x 512 threads (8 waves). wave wu: oct o=wu>>1 (8 neurons),
// tap half th=wu&1 (60/61 taps), 64 rows. Weight loads use a VGPR-derived
// oct index so they stay VMEM (vmcnt domain) and double-buffer 2 taps deep.
__global__ __launch_bounds__(512, 4) void stage1_kernel(
    const float* __restrict__ x, const float* __restrict__ W0,
    const float* __restrict__ b0, const float* __restrict__ WcBc,
    float* __restrict__ y) {
  __shared__ float4 sXv[TL + 120];      // 184 * 16 B = 2944 B
  __shared__ float4 sPre[16 * 64];      // [4o+2th+q][row] = 16 KB
  __shared__ float4 sYq[8 * 64];        // [quad][row] = 8 KB

  const int b    = blockIdx.x >> 6;     // 8 batches x 64 tiles
  const int tile = blockIdx.x & 63;
  const int l0   = tile * TL;
  const int tid  = threadIdx.x;
  const int lane = tid & 63;

  const float4* xv = (const float4*)(x + (size_t)b * L_SEQ * 4);
  for (int i = tid; i < TL + 120; i += 512)
    sXv[i] = xv[(l0 - 120 + i) & (L_SEQ - 1)];
  __syncthreads();

  const int wu = __builtin_amdgcn_readfirstlane(tid >> 6);  // 0..7 uniform
  const int th = wu & 1;                 // tap half
  const int d0 = th * 60;
  const int dn = th ? 61 : 60;           // 60 + 61 = 121
  const int ov = (threadIdx.x >> 7) & 3; // oct 0..3 — VGPR (forces VMEM loads)

  const float4* __restrict__ W0v = (const float4*)W0;

  float acc[8];
#pragma unroll
  for (int n = 0; n < 8; ++n) acc[n] = 0.f;

  // weight float4 index for (d,c,q): (d*4+c)*8 + ov*2 + q
#define LOADW(dst, dtap)                                            \
  {                                                                 \
    const int base_ = (dtap) * 32 + ov * 2;                         \
    _Pragma("unroll")                                               \
    for (int c_ = 0; c_ < 4; ++c_) {                                \
      dst[c_ * 2 + 0] = W0v[base_ + c_ * 8 + 0];                    \
      dst[c_ * 2 + 1] = W0v[base_ + c_ * 8 + 1];                    \
    }                                                               \
  }

#define FMA8(wset, xc)                                              \
  {                                                                 \
    _Pragma("unroll")                                               \
    for (int c_ = 0; c_ < 4; ++c_) {                                \
      const float xs_ = ((const float*)&(xc))[c_];                  \
      const float4 wq0_ = wset[c_ * 2 + 0];                         \
      const float4 wq1_ = wset[c_ * 2 + 1];                         \
      acc[0] = fmaf(xs_, wq0_.x, acc[0]);                           \
      acc[1] = fmaf(xs_, wq0_.y, acc[1]);                           \
      acc[2] = fmaf(xs_, wq0_.z, acc[2]);                           \
      acc[3] = fmaf(xs_, wq0_.w, acc[3]);                           \
      acc[4] = fmaf(xs_, wq1_.x, acc[4]);                           \
      acc[5] = fmaf(xs_, wq1_.y, acc[5]);                           \
      acc[6] = fmaf(xs_, wq1_.z, acc[6]);                           \
      acc[7] = fmaf(xs_, wq1_.w, acc[7]);                           \
    }                                                               \
  }

  float4 wA[8], wB[8];
  LOADW(wA, d0);
  float4 xcur = sXv[lane + d0];

  int dd = 0;
  for (; dd + 2 <= dn; dd += 2) {
    const int d1   = d0 + dd + 1;
    const bool more = (dd + 2 < dn);
    const int d2   = more ? (d0 + dd + 2) : d0;     // clamped dummy reload
    LOADW(wB, d1);
    const float4 xn1 = sXv[lane + d1];
    FMA8(wA, xcur);
    LOADW(wA, d2);
    const float4 xn2 = sXv[lane + d2];
    FMA8(wB, xn1);
    xcur = xn2;
  }
  if (dd < dn) {            // odd tail (th=1: 61 taps)
    FMA8(wA, xcur);
  }
#undef LOADW
#undef FMA8

  // scatter pre-tanh partials: row (wu*2+q) = 4*oct + 2*th + q
#pragma unroll
  for (int q = 0; q < 2; ++q) {
    float4 v;
    v.x = acc[q*4+0]; v.y = acc[q*4+1]; v.z = acc[q*4+2]; v.w = acc[q*4+3];
    sPre[(wu * 2 + q) * 64 + lane] = v;
  }
  __syncthreads();

  // wave wu == quad g: neurons 4g..4g+3 (oct g>>1, q g&1).
  {
    const int g  = wu;
    const int o2 = g >> 1;
    const int qq = g & 1;
    const float4 pa = sPre[(4 * o2 + 0 + qq) * 64 + lane];
    const float4 pb = sPre[(4 * o2 + 2 + qq) * 64 + lane];
    const float4 bb = ((const float4*)b0)[g];               // uniform
    const float h0 = 1.f - 2.f / (__expf(2.f * (pa.x + pb.x + bb.x)) + 1.f);
    const float h1 = 1.f - 2.f / (__expf(2.f * (pa.y + pb.y + bb.y)) + 1.f);
    const float h2 = 1.f - 2.f / (__expf(2.f * (pa.z + pb.z + bb.z)) + 1.f);
    const float h3 = 1.f - 2.f / (__expf(2.f * (pa.w + pb.w + bb.w)) + 1.f);
    const float4 wc0 = ((const float4*)WcBc)[4 * g + 0];    // uniform
    const float4 wc1 = ((const float4*)WcBc)[4 * g + 1];
    const float4 wc2 = ((const float4*)WcBc)[4 * g + 2];
    const float4 wc3 = ((const float4*)WcBc)[4 * g + 3];
    float4 yp;
    yp.x = h0*wc0.x + h1*wc1.x + h2*wc2.x + h3*wc3.x;
    yp.y = h0*wc0.y + h1*wc1.y + h2*wc2.y + h3*wc3.y;
    yp.z = h0*wc0.z + h1*wc1.z + h2*wc2.z + h3*wc3.z;
    yp.w = h0*wc0.w + h1*wc1.w + h2*wc2.w + h3*wc3.w;
    sYq[g * 64 + lane] = yp;
  }
  __syncthreads();

  if (tid < TL) {
    float4 o;
    o.x = WcBc[128 + 0]; o.y = WcBc[128 + 1];
    o.z = WcBc[128 + 2]; o.w = WcBc[128 + 3];
#pragma unroll
    for (int g2 = 0; g2 < 8; ++g2) {
      const float4 p = sYq[g2 * 64 + tid];
      o.x += p.x; o.y += p.y; o.z += p.z; o.w += p.w;
    }
    ((float4*)(y + (size_t)b * L_SEQ * 4))[l0 + tid] = o;
  }
}

// ---------------- stage2: out = relu(win5(y) @ W2 + b2) @ W3 + b3 ----------------
__global__ __launch_bounds__(128) void stage2_kernel(
    const float* __restrict__ y, const float* __restrict__ W2,
    const float* __restrict__ b2, const float* __restrict__ W3,
    const float* __restrict__ b3, float* __restrict__ out) {
  const int g = blockIdx.x * 128 + threadIdx.x;  // 0..32767
  const int b = g >> 12;
  const int l = g & (L_SEQ - 1);
  const float4* yv = (const float4*)(y + (size_t)b * L_SEQ * 4);

  float win[20];
#pragma unroll
  for (int j = 0; j < 5; ++j) {
    const float4 v = yv[(l - 4 + j) & (L_SEQ - 1)];
    win[j*4+0] = v.x; win[j*4+1] = v.y; win[j*4+2] = v.z; win[j*4+3] = v.w;
  }

  float h[32];
#pragma unroll
  for (int n = 0; n < 32; ++n) h[n] = b2[n];
#pragma unroll
  for (int k = 0; k < 20; ++k) {
    const float xs = win[k];
#pragma unroll
    for (int n = 0; n < 32; ++n) h[n] = fmaf(xs, W2[k*32 + n], h[n]);
  }

  float o[4];
#pragma unroll
  for (int j = 0; j < 4; ++j) o[j] = b3[j];
#pragma unroll
  for (int n = 0; n < 32; ++n) {
    const float hv = fmaxf(h[n], 0.f);
#pragma unroll
    for (int j = 0; j < 4; ++j) o[j] = fmaf(hv, W3[n*4 + j], o[j]);
  }
  float4 ov;
  ((float*)&ov)[0] = o[0]; ((float*)&ov)[1] = o[1];
  ((float*)&ov)[2] = o[2]; ((float*)&ov)[3] = o[3];
  ((float4*)out)[g] = ov;
}

extern "C" void kernel_launch(void* const* d_in, const int* in_sizes, int n_in,
                              void* d_out, int out_size, void* d_ws, size_t ws_size,
                              hipStream_t stream) {
  const float* x  = (const float*)d_in[0];   // [8,4096,4]
  const float* W0 = (const float*)d_in[1];   // [484,32]
  const float* b0 = (const float*)d_in[2];   // [32]
  const float* W1 = (const float*)d_in[3];   // [32,512]
  const float* b1 = (const float*)d_in[4];   // [512]
  const float* Ws = (const float*)d_in[5];   // [512,4096]
  const float* bs = (const float*)d_in[6];   // [4096]
  const float* Wr = (const float*)d_in[7];   // [4096,4]
  const float* br = (const float*)d_in[8];   // [4]
  const float* W2 = (const float*)d_in[9];   // [20,32]
  const float* b2 = (const float*)d_in[10];  // [32]
  const float* W3 = (const float*)d_in[11];  // [32,4]
  const float* b3 = (const float*)d_in[12];  // [4]
  float* outp = (float*)d_out;               // [8,4096,4]

  // workspace (floats): T[513*4]=2052 @0, WcBc[132] @2052, y[131072] @2304
  float* T    = (float*)d_ws;
  float* WcBc = T + 2052;
  float* y    = (float*)d_ws + 2304;   // 16B-aligned

  precomp1_kernel<<<129, 256, 0, stream>>>(Ws, bs, Wr, T);
  precomp2_kernel<<<33, 128, 0, stream>>>(W1, b1, br, T, WcBc);
  stage1_kernel<<<512, 512, 0, stream>>>(x, W0, b0, WcBc, y);
  stage2_kernel<<<256, 128, 0, stream>>>(y, W2, b2, W3, b3, outp);
}

// Round 7
// 109.709 us; speedup vs baseline: 1.4888x; 1.4888x over previous
//
#include <hip/hip_runtime.h>
#include <hip/hip_bf16.h>
#include <math.h>

// Model_58488864637193 — algebraic collapse of the 3 stacked linears:
//   Wc = W1 @ (Ws @ Wr)  [32,4],  bc = (b1 @ (Ws@Wr)) + bs@Wr + br  [4]
// Work: 141 GFLOP -> ~1.1 GFLOP, dominated by the ring-121 484->32 tanh layer.
//
// R6 -> R7: both SMEM and VMEM weight streaming are operand-delivery-bound
// (~128B weights per 64 FMA-cyc per wave). Stage1 is really a GEMM
// A[64x484] (sliding-window im2col, implicit in LDS) x W0[484x32] -> use
// mfma_f32_16x16x32_bf16. K padded 484->512 (16 chunks); B-frags precomputed
// in fragment order (zero-padded) by precompW; A-frags are two ds_read_b64
// from the contiguous bf16 [pos][ch] window. fp32 accumulate; bias+tanh on
// C-frags (layout col=lane&15, row=(lane>>4)*4+reg, m89-verified); Wc fold
// via padded LDS [64][33].

#define L_SEQ 4096

typedef __attribute__((ext_vector_type(8))) short  bf16x8;
typedef __attribute__((ext_vector_type(4))) float  f32x4;

static __device__ __forceinline__ unsigned short f2bf(float f) {
  union { float f; unsigned int u; } v; v.f = f;
  unsigned int u = v.u + 0x7fffu + ((v.u >> 16) & 1u);   // RTNE
  return (unsigned short)(u >> 16);
}

// ---------------- precomp1: T[513][4] = [Ws; bs] @ Wr ----------------
__global__ __launch_bounds__(256) void precomp1_kernel(
    const float* __restrict__ Ws, const float* __restrict__ bs,
    const float* __restrict__ Wr, float* __restrict__ T) {
  const int tid  = threadIdx.x;
  const int k    = blockIdx.x * 4 + (tid >> 6);   // wave id = output row
  const int lane = tid & 63;
  if (k >= 513) return;
  const float4* row4 = (const float4*)((k < 512) ? (Ws + (size_t)k * 4096) : bs);
  const float4* Wr4  = (const float4*)Wr;
  float a0 = 0.f, a1 = 0.f, a2 = 0.f, a3 = 0.f;
#pragma unroll 4
  for (int m4 = lane; m4 < 1024; m4 += 64) {
    const float4 rv = row4[m4];
#pragma unroll
    for (int c = 0; c < 4; ++c) {
      const float  xs = ((const float*)&rv)[c];
      const float4 w  = Wr4[m4 * 4 + c];
      a0 = fmaf(xs, w.x, a0); a1 = fmaf(xs, w.y, a1);
      a2 = fmaf(xs, w.z, a2); a3 = fmaf(xs, w.w, a3);
    }
  }
#pragma unroll
  for (int off = 32; off > 0; off >>= 1) {
    a0 += __shfl_xor(a0, off); a1 += __shfl_xor(a1, off);
    a2 += __shfl_xor(a2, off); a3 += __shfl_xor(a3, off);
  }
  if (lane == 0) {
    float4 o; o.x = a0; o.y = a1; o.z = a2; o.w = a3;
    ((float4*)T)[k] = o;
  }
}

// ---------------- precomp2: WcBc[132] = {Wc[32][4] row-major, bc[4]} ----------------
__global__ __launch_bounds__(128) void precomp2_kernel(
    const float* __restrict__ W1, const float* __restrict__ b1,
    const float* __restrict__ br, const float* __restrict__ T,
    float* __restrict__ WcBc) {
  const int i   = blockIdx.x;        // 0..32
  const int t   = threadIdx.x;       // 0..127
  const int j   = t & 3;
  const int seg = t >> 2;            // 0..31
  const float4* v4 = (const float4*)((i < 32) ? (W1 + (size_t)i * 512) : b1);
  const float4* T4 = (const float4*)T;
  float acc = 0.f;
#pragma unroll
  for (int q = 0; q < 4; ++q) {
    const int m4 = seg * 4 + q;
    const float4 vv = v4[m4];
#pragma unroll
    for (int c = 0; c < 4; ++c) {
      const float4 trow = T4[m4 * 4 + c];
      acc = fmaf(((const float*)&vv)[c], ((const float*)&trow)[j], acc);
    }
  }
  __shared__ float red[128];
  red[t] = acc;
  __syncthreads();
#pragma unroll
  for (int s = 64; s >= 4; s >>= 1) {
    if (t < s) red[t] += red[t + s];
    __syncthreads();
  }
  if (t < 4) {
    float r = red[t];
    if (i == 32) r += T[512 * 4 + t] + br[t];
    WcBc[(i < 32 ? i * 4 : 128) + t] = r;
  }
}

// ---------------- precompW: W0 -> bf16 B-fragments in MFMA order ----------------
// frag f = kk*2+nh (kk=0..15 k-chunk, nh=0..1 neuron half); lane l holds
// B[k=kk*32+8*(l>>4)+j][n=nh*16+(l&15)], j=0..7; zero-padded for k>=484.
__global__ __launch_bounds__(256) void precompW_kernel(
    const float* __restrict__ W0, unsigned short* __restrict__ Bfrag) {
  const int t  = blockIdx.x * 256 + threadIdx.x;   // 0..2047
  const int f  = t >> 6;
  const int l  = t & 63;
  const int kk = f >> 1;
  const int nh = f & 1;
  const int n  = nh * 16 + (l & 15);
  unsigned int pk[4];
#pragma unroll
  for (int p = 0; p < 4; ++p) {
    const int k0 = kk * 32 + (l >> 4) * 8 + p * 2;
    const float v0 = (k0     < 484) ? W0[(size_t)k0 * 32 + n]       : 0.f;
    const float v1 = (k0 + 1 < 484) ? W0[(size_t)(k0 + 1) * 32 + n] : 0.f;
    pk[p] = (unsigned int)f2bf(v0) | ((unsigned int)f2bf(v1) << 16);
  }
  uint4 o; o.x = pk[0]; o.y = pk[1]; o.z = pk[2]; o.w = pk[3];
  ((uint4*)Bfrag)[t] = o;
}

// ---------------- stage1: y = tanh(win121(x) @ W0 + b0) @ Wc + bc ----------------
// 512 blocks x 256 threads (4 waves). Wave w owns rows w*16..+15 of the
// 64-row tile; 16 K-chunks x 2 N-halves of mfma_f32_16x16x32_bf16.
__global__ __launch_bounds__(256) void stage1_kernel(
    const float* __restrict__ x, const unsigned short* __restrict__ Bfrag,
    const float* __restrict__ b0, const float* __restrict__ WcBc,
    float* __restrict__ y) {
  __shared__ unsigned short sX[192 * 4];   // [pos][ch] bf16, 1536 B
  __shared__ float sH[64][33];             // padded: conflict-free
  __shared__ float sWc[132];               // Wc + bc

  const int b    = blockIdx.x >> 6;        // 8 batches x 64 tiles
  const int tile = blockIdx.x & 63;
  const int l0   = tile * 64;
  const int tid  = threadIdx.x;

  // stage x window as bf16: pos 0..183 real (rows l0-120..l0+63), 184..191 zero
  if (tid < 192) {
    float4 v = {0.f, 0.f, 0.f, 0.f};
    if (tid < 184)
      v = ((const float4*)(x + (size_t)b * L_SEQ * 4))[(l0 - 120 + tid) & (L_SEQ - 1)];
    ushort4 u;
    u.x = f2bf(v.x); u.y = f2bf(v.y); u.z = f2bf(v.z); u.w = f2bf(v.w);
    *(ushort4*)(sX + tid * 4) = u;
  }
  if (tid < 132) sWc[tid] = WcBc[tid];
  __syncthreads();

  const int lane = tid & 63;
  const int wid  = tid >> 6;               // 0..3 -> rows wid*16..+15
  const int rowb = wid * 16;

  // load all 32 B-frags (identical addresses across waves -> L1 broadcast)
  const bf16x8* Bf = (const bf16x8*)Bfrag;
  bf16x8 bw[32];
#pragma unroll
  for (int f = 0; f < 32; ++f) bw[f] = Bf[f * 64 + lane];

  const float bias0 = b0[lane & 15];
  const float bias1 = b0[16 + (lane & 15)];

  f32x4 acc0 = {0.f, 0.f, 0.f, 0.f};
  f32x4 acc1 = {0.f, 0.f, 0.f, 0.f};

#pragma unroll
  for (int kk = 0; kk < 16; ++kk) {
    // A-frag: lane l -> row rowb+(l&15), taps kk*8+2*(l>>4)+{0,1}, 4 ch each
    const int p0 = rowb + (lane & 15) + kk * 8 + 2 * (lane >> 4);
    union { uint4 u; bf16x8 v; } af;
    const uint2 lo = *(const uint2*)(sX + p0 * 4);
    const uint2 hi = *(const uint2*)(sX + p0 * 4 + 4);
    af.u.x = lo.x; af.u.y = lo.y; af.u.z = hi.x; af.u.w = hi.y;
    acc0 = __builtin_amdgcn_mfma_f32_16x16x32_bf16(af.v, bw[kk * 2 + 0], acc0, 0, 0, 0);
    acc1 = __builtin_amdgcn_mfma_f32_16x16x32_bf16(af.v, bw[kk * 2 + 1], acc1, 0, 0, 0);
  }

  // bias + tanh, write H to LDS (C layout: col=lane&15, row=(lane>>4)*4+reg)
#pragma unroll
  for (int r = 0; r < 4; ++r) {
    const int row = rowb + (lane >> 4) * 4 + r;
    const float s0 = acc0[r] + bias0;
    const float s1 = acc1[r] + bias1;
    sH[row][lane & 15]      = 1.f - 2.f / (__expf(2.f * s0) + 1.f);
    sH[row][16 + (lane & 15)] = 1.f - 2.f / (__expf(2.f * s1) + 1.f);
  }
  __syncthreads();

  // fold through Wc: thread (rr, j) -> y[b][l0+rr][j]
  {
    const int rr = tid >> 2;
    const int j  = tid & 3;
    float o = sWc[128 + j];
#pragma unroll
    for (int n = 0; n < 32; ++n) o = fmaf(sH[rr][n], sWc[n * 4 + j], o);
    y[((size_t)b * L_SEQ + l0 + rr) * 4 + j] = o;
  }
}

// ---------------- stage2: out = relu(win5(y) @ W2 + b2) @ W3 + b3 ----------------
__global__ __launch_bounds__(128) void stage2_kernel(
    const float* __restrict__ y, const float* __restrict__ W2,
    const float* __restrict__ b2, const float* __restrict__ W3,
    const float* __restrict__ b3, float* __restrict__ out) {
  const int g = blockIdx.x * 128 + threadIdx.x;  // 0..32767
  const int b = g >> 12;
  const int l = g & (L_SEQ - 1);
  const float4* yv = (const float4*)(y + (size_t)b * L_SEQ * 4);

  float win[20];
#pragma unroll
  for (int j = 0; j < 5; ++j) {
    const float4 v = yv[(l - 4 + j) & (L_SEQ - 1)];
    win[j*4+0] = v.x; win[j*4+1] = v.y; win[j*4+2] = v.z; win[j*4+3] = v.w;
  }

  float h[32];
#pragma unroll
  for (int n = 0; n < 32; ++n) h[n] = b2[n];
#pragma unroll
  for (int k = 0; k < 20; ++k) {
    const float xs = win[k];
#pragma unroll
    for (int n = 0; n < 32; ++n) h[n] = fmaf(xs, W2[k*32 + n], h[n]);
  }

  float o[4];
#pragma unroll
  for (int j = 0; j < 4; ++j) o[j] = b3[j];
#pragma unroll
  for (int n = 0; n < 32; ++n) {
    const float hv = fmaxf(h[n], 0.f);
#pragma unroll
    for (int j = 0; j < 4; ++j) o[j] = fmaf(hv, W3[n*4 + j], o[j]);
  }
  float4 ov;
  ((float*)&ov)[0] = o[0]; ((float*)&ov)[1] = o[1];
  ((float*)&ov)[2] = o[2]; ((float*)&ov)[3] = o[3];
  ((float4*)out)[g] = ov;
}

extern "C" void kernel_launch(void* const* d_in, const int* in_sizes, int n_in,
                              void* d_out, int out_size, void* d_ws, size_t ws_size,
                              hipStream_t stream) {
  const float* x  = (const float*)d_in[0];   // [8,4096,4]
  const float* W0 = (const float*)d_in[1];   // [484,32]
  const float* b0 = (const float*)d_in[2];   // [32]
  const float* W1 = (const float*)d_in[3];   // [32,512]
  const float* b1 = (const float*)d_in[4];   // [512]
  const float* Ws = (const float*)d_in[5];   // [512,4096]
  const float* bs = (const float*)d_in[6];   // [4096]
  const float* Wr = (const float*)d_in[7];   // [4096,4]
  const float* br = (const float*)d_in[8];   // [4]
  const float* W2 = (const float*)d_in[9];   // [20,32]
  const float* b2 = (const float*)d_in[10];  // [32]
  const float* W3 = (const float*)d_in[11];  // [32,4]
  const float* b3 = (const float*)d_in[12];  // [4]
  float* outp = (float*)d_out;               // [8,4096,4]

  // ws (floats): T[2052] @0, WcBc[132] @2052, y[131072] @2304,
  //              Bfrag (16384 ushort = 32KB) @133376
  float* T    = (float*)d_ws;
  float* WcBc = T + 2052;
  float* y    = (float*)d_ws + 2304;
  unsigned short* Bfrag = (unsigned short*)((float*)d_ws + 133376);

  precomp1_kernel<<<129, 256, 0, stream>>>(Ws, bs, Wr, T);
  precomp2_kernel<<<33, 128, 0, stream>>>(W1, b1, br, T, WcBc);
  precompW_kernel<<<8, 256, 0, stream>>>(W0, Bfrag);
  stage1_kernel<<<512, 256, 0, stream>>>(x, Bfrag, b0, WcBc, y);
  stage2_kernel<<<256, 128, 0, stream>>>(y, W2, b2, W3, b3, outp);
}

// Round 8
// 106.983 us; speedup vs baseline: 1.5267x; 1.0255x over previous
//
#include <hip/hip_runtime.h>
#include <hip/hip_bf16.h>
#include <math.h>

// Model_58488864637193 — algebraic collapse of the 3 stacked linears:
//   Wc = W1 @ (Ws @ Wr)  [32,4],  bc = (b1 @ (Ws@Wr)) + bs@Wr + br  [4]
// Work: 141 GFLOP -> ~1.1 GFLOP, dominated by the ring-121 484->32 tanh layer
// (done as an MFMA GEMM since R7: A[rows x 484] im2col in LDS, bf16).
//
// R7 -> R8: measured floor is ~82 us of harness 0xAA poison-fills (2 x 256 MB
// at ~6.6 TB/s) + ~1.5 us per launch gap; our kernels are ~25 us total. So:
// (a) stage2 fused into stage1 via a 4-row ring halo (each block computes 68
//     y-rows in LDS: 5 waves, M=80, 18% MFMA waste) — kills one kernel, one
//     gap, and the y round-trip;
// (b) precomp2 + precompW merged into one kernel (branch on blockIdx) — kills
//     another gap. 5 kernels -> 3.

#define L_SEQ 4096
#define NPOS  208   // sX positions: 0..187 real (x rows l0-124..l0+63), rest 0

typedef __attribute__((ext_vector_type(8))) short  bf16x8;
typedef __attribute__((ext_vector_type(4))) float  f32x4;

static __device__ __forceinline__ unsigned short f2bf(float f) {
  union { float f; unsigned int u; } v; v.f = f;
  unsigned int u = v.u + 0x7fffu + ((v.u >> 16) & 1u);   // RTNE
  return (unsigned short)(u >> 16);
}

// ---------------- precomp1: T[513][4] = [Ws; bs] @ Wr ----------------
__global__ __launch_bounds__(256) void precomp1_kernel(
    const float* __restrict__ Ws, const float* __restrict__ bs,
    const float* __restrict__ Wr, float* __restrict__ T) {
  const int tid  = threadIdx.x;
  const int k    = blockIdx.x * 4 + (tid >> 6);   // wave id = output row
  const int lane = tid & 63;
  if (k >= 513) return;
  const float4* row4 = (const float4*)((k < 512) ? (Ws + (size_t)k * 4096) : bs);
  const float4* Wr4  = (const float4*)Wr;
  float a0 = 0.f, a1 = 0.f, a2 = 0.f, a3 = 0.f;
#pragma unroll 4
  for (int m4 = lane; m4 < 1024; m4 += 64) {
    const float4 rv = row4[m4];
#pragma unroll
    for (int c = 0; c < 4; ++c) {
      const float  xs = ((const float*)&rv)[c];
      const float4 w  = Wr4[m4 * 4 + c];
      a0 = fmaf(xs, w.x, a0); a1 = fmaf(xs, w.y, a1);
      a2 = fmaf(xs, w.z, a2); a3 = fmaf(xs, w.w, a3);
    }
  }
#pragma unroll
  for (int off = 32; off > 0; off >>= 1) {
    a0 += __shfl_xor(a0, off); a1 += __shfl_xor(a1, off);
    a2 += __shfl_xor(a2, off); a3 += __shfl_xor(a3, off);
  }
  if (lane == 0) {
    float4 o; o.x = a0; o.y = a1; o.z = a2; o.w = a3;
    ((float4*)T)[k] = o;
  }
}

// ---------------- precomp_small: blocks 0..32 -> WcBc; 33..40 -> Bfrag ----------------
// WcBc[132] = {Wc[32][4] row-major, bc[4]};  Bfrag = W0 as bf16 MFMA B-frags:
// frag f=kk*2+nh, lane l holds B[k=kk*32+8*(l>>4)+j][n=nh*16+(l&15)], j=0..7,
// zero-padded for k>=484.
__global__ __launch_bounds__(256) void precomp_small_kernel(
    const float* __restrict__ W1, const float* __restrict__ b1,
    const float* __restrict__ br, const float* __restrict__ T,
    float* __restrict__ WcBc,
    const float* __restrict__ W0, unsigned short* __restrict__ Bfrag) {
  if (blockIdx.x < 33) {
    const int i = blockIdx.x;        // 0..32 (32 -> b1 row)
    const int t = threadIdx.x;
    __shared__ float red[128];
    float acc = 0.f;
    if (t < 128) {
      const int j   = t & 3;
      const int seg = t >> 2;        // 0..31
      const float4* v4 = (const float4*)((i < 32) ? (W1 + (size_t)i * 512) : b1);
      const float4* T4 = (const float4*)T;
#pragma unroll
      for (int q = 0; q < 4; ++q) {
        const int m4 = seg * 4 + q;
        const float4 vv = v4[m4];
#pragma unroll
        for (int c = 0; c < 4; ++c) {
          const float4 trow = T4[m4 * 4 + c];
          acc = fmaf(((const float*)&vv)[c], ((const float*)&trow)[j], acc);
        }
      }
      red[t] = acc;
    }
    __syncthreads();
#pragma unroll
    for (int s = 64; s >= 4; s >>= 1) {
      if (t < s) red[t] += red[t + s];
      __syncthreads();
    }
    if (t < 4) {
      float r = red[t];
      if (i == 32) r += T[512 * 4 + t] + br[t];
      WcBc[(i < 32 ? i * 4 : 128) + t] = r;
    }
  } else {
    const int t  = (blockIdx.x - 33) * 256 + threadIdx.x;  // 0..2047
    const int f  = t >> 6;
    const int l  = t & 63;
    const int kk = f >> 1;
    const int nh = f & 1;
    const int n  = nh * 16 + (l & 15);
    unsigned int pk[4];
#pragma unroll
    for (int p = 0; p < 4; ++p) {
      const int k0 = kk * 32 + (l >> 4) * 8 + p * 2;
      const float v0 = (k0     < 484) ? W0[(size_t)k0 * 32 + n]       : 0.f;
      const float v1 = (k0 + 1 < 484) ? W0[(size_t)(k0 + 1) * 32 + n] : 0.f;
      pk[p] = (unsigned int)f2bf(v0) | ((unsigned int)f2bf(v1) << 16);
    }
    uint4 o; o.x = pk[0]; o.y = pk[1]; o.z = pk[2]; o.w = pk[3];
    ((uint4*)Bfrag)[t] = o;
  }
}

// ---------------- stage12: full fused pipeline per 64-row tile ----------------
// 512 blocks x 320 threads (5 waves). Block computes 68 y-rows (l0-4..l0+63,
// ring) via MFMA (M=80, rows 68..79 junk), folds through Wc into LDS, then
// the ring-5 relu layer + final projection for its 64 output rows.
__global__ __launch_bounds__(320) void stage12_kernel(
    const float* __restrict__ x, const unsigned short* __restrict__ Bfrag,
    const float* __restrict__ b0, const float* __restrict__ WcBc,
    const float* __restrict__ W2, const float* __restrict__ b2,
    const float* __restrict__ W3, const float* __restrict__ b3,
    float* __restrict__ out) {
  __shared__ unsigned short sX[NPOS * 4];  // [pos][ch] bf16, 1664 B
  __shared__ float sH[68][33];             // tanh outputs, padded (conflict-free)
  __shared__ float sYv[68][4];             // y rows l0-4..l0+63
  __shared__ float sWc[132];               // Wc + bc

  const int b    = blockIdx.x >> 6;        // 8 batches x 64 tiles
  const int tile = blockIdx.x & 63;
  const int l0   = tile * 64;
  const int tid  = threadIdx.x;

  // stage x window as bf16: pos p <-> x row (l0-124+p) mod L; p>=188 zero
  if (tid < NPOS) {
    float4 v = {0.f, 0.f, 0.f, 0.f};
    if (tid < 188)
      v = ((const float4*)(x + (size_t)b * L_SEQ * 4))[(l0 - 124 + tid) & (L_SEQ - 1)];
    ushort4 u;
    u.x = f2bf(v.x); u.y = f2bf(v.y); u.z = f2bf(v.z); u.w = f2bf(v.w);
    *(ushort4*)(sX + tid * 4) = u;
  }
  if (tid < 132) sWc[tid] = WcBc[tid];
  __syncthreads();

  const int lane = tid & 63;
  const int wid  = tid >> 6;               // 0..4 -> A-rows wid*16..+15
  const int rowb = wid * 16;

  // all 32 B-frags (same addresses across waves -> L1 broadcast)
  const bf16x8* Bf = (const bf16x8*)Bfrag;
  bf16x8 bw[32];
#pragma unroll
  for (int f = 0; f < 32; ++f) bw[f] = Bf[f * 64 + lane];

  const float bias0 = b0[lane & 15];
  const float bias1 = b0[16 + (lane & 15)];

  f32x4 acc0 = {0.f, 0.f, 0.f, 0.f};
  f32x4 acc1 = {0.f, 0.f, 0.f, 0.f};

#pragma unroll
  for (int kk = 0; kk < 16; ++kk) {
    // A-frag: lane l -> A-row rowb+(l&15), taps kk*8+2*(l>>4)+{0,1}, 4 ch each
    const int p0 = rowb + (lane & 15) + kk * 8 + 2 * (lane >> 4);
    union { uint4 u; bf16x8 v; } af;
    const uint2 lo = *(const uint2*)(sX + p0 * 4);
    const uint2 hi = *(const uint2*)(sX + p0 * 4 + 4);
    af.u.x = lo.x; af.u.y = lo.y; af.u.z = hi.x; af.u.w = hi.y;
    acc0 = __builtin_amdgcn_mfma_f32_16x16x32_bf16(af.v, bw[kk * 2 + 0], acc0, 0, 0, 0);
    acc1 = __builtin_amdgcn_mfma_f32_16x16x32_bf16(af.v, bw[kk * 2 + 1], acc1, 0, 0, 0);
  }

  // bias + tanh -> sH (C layout: col=lane&15, row=rowb+(lane>>4)*4+reg)
#pragma unroll
  for (int r = 0; r < 4; ++r) {
    const int row = rowb + (lane >> 4) * 4 + r;
    if (row < 68) {
      const float s0 = acc0[r] + bias0;
      const float s1 = acc1[r] + bias1;
      sH[row][lane & 15]        = 1.f - 2.f / (__expf(2.f * s0) + 1.f);
      sH[row][16 + (lane & 15)] = 1.f - 2.f / (__expf(2.f * s1) + 1.f);
    }
  }
  __syncthreads();

  // fold through Wc: y-row (l0-4+rr) -> sYv[rr]
  if (tid < 272) {
    const int rr = tid >> 2;
    const int j  = tid & 3;
    float o = sWc[128 + j];
#pragma unroll
    for (int n = 0; n < 32; ++n) o = fmaf(sH[rr][n], sWc[n * 4 + j], o);
    sYv[rr][j] = o;
  }
  __syncthreads();

  // ring-5 relu layer + final projection; thread (rr, j) -> out[b][l0+rr][j]
  if (tid < 256) {
    const int rr = tid >> 2;
    const int j  = tid & 3;
    float win[20];
#pragma unroll
    for (int jj = 0; jj < 5; ++jj) {
      const float4 v = *(const float4*)&sYv[rr + jj][0];   // y row l0+rr-4+jj
      win[jj*4+0] = v.x; win[jj*4+1] = v.y; win[jj*4+2] = v.z; win[jj*4+3] = v.w;
    }
    float h[32];
#pragma unroll
    for (int n = 0; n < 32; ++n) h[n] = b2[n];
#pragma unroll
    for (int k = 0; k < 20; ++k) {
      const float xs = win[k];
#pragma unroll
      for (int n = 0; n < 32; ++n) h[n] = fmaf(xs, W2[k*32 + n], h[n]);
    }
    float o = b3[j];
#pragma unroll
    for (int n = 0; n < 32; ++n)
      o = fmaf(fmaxf(h[n], 0.f), W3[n*4 + j], o);
    out[((size_t)b * L_SEQ + l0 + rr) * 4 + j] = o;
  }
}

extern "C" void kernel_launch(void* const* d_in, const int* in_sizes, int n_in,
                              void* d_out, int out_size, void* d_ws, size_t ws_size,
                              hipStream_t stream) {
  const float* x  = (const float*)d_in[0];   // [8,4096,4]
  const float* W0 = (const float*)d_in[1];   // [484,32]
  const float* b0 = (const float*)d_in[2];   // [32]
  const float* W1 = (const float*)d_in[3];   // [32,512]
  const float* b1 = (const float*)d_in[4];   // [512]
  const float* Ws = (const float*)d_in[5];   // [512,4096]
  const float* bs = (const float*)d_in[6];   // [4096]
  const float* Wr = (const float*)d_in[7];   // [4096,4]
  const float* br = (const float*)d_in[8];   // [4]
  const float* W2 = (const float*)d_in[9];   // [20,32]
  const float* b2 = (const float*)d_in[10];  // [32]
  const float* W3 = (const float*)d_in[11];  // [32,4]
  const float* b3 = (const float*)d_in[12];  // [4]
  float* outp = (float*)d_out;               // [8,4096,4]

  // ws (floats): T[2052] @0, WcBc[132] @2052, Bfrag (16384 ushort) @2304
  float* T    = (float*)d_ws;
  float* WcBc = T + 2052;
  unsigned short* Bfrag = (unsigned short*)((float*)d_ws + 2304);

  precomp1_kernel<<<129, 256, 0, stream>>>(Ws, bs, Wr, T);
  precomp_small_kernel<<<41, 256, 0, stream>>>(W1, b1, br, T, WcBc, W0, Bfrag);
  stage12_kernel<<<512, 320, 0, stream>>>(x, Bfrag, b0, WcBc, W2, b2, W3, b3, outp);
}

// Round 9
// 105.043 us; speedup vs baseline: 1.5549x; 1.0185x over previous
//
#include <hip/hip_runtime.h>
#include <hip/hip_bf16.h>
#include <math.h>

// Model_58488864637193 — algebraic collapse of the 3 stacked linears:
//   Wc = W1 @ (Ws @ Wr)  [32,4],  bc = (b1 @ (Ws@Wr)) + bs@Wr + br  [4]
// Work: 141 GFLOP -> ~1.1 GFLOP; the ring-121 484->32 tanh layer runs as an
// MFMA GEMM (A[80x484] im2col in LDS, bf16, K padded to 512).
//
// R8 -> R9: measured floor = 2 x 256MB ws-poison fills (~84 us) + restore
// (~3 us); ours ~20 us. stage12's stage2 tail was 4x redundant (each of 4
// j-lanes computed all h[32]). Now thread (rr,jg) computes only neurons
// jg*8..+7 (W2 from LDS, conflict-free by construction), partial o[4] via
// register-resident W3 rows, then 2-step shfl_xor butterfly over the 4
// jg-lanes; lane jg writes out[..][jg]. 768 -> 192 FMA/thread.

#define L_SEQ 4096
#define NPOS  208   // sX positions: 0..187 real (x rows l0-124..l0+63), rest 0

typedef __attribute__((ext_vector_type(8))) short  bf16x8;
typedef __attribute__((ext_vector_type(4))) float  f32x4;

static __device__ __forceinline__ unsigned short f2bf(float f) {
  union { float f; unsigned int u; } v; v.f = f;
  unsigned int u = v.u + 0x7fffu + ((v.u >> 16) & 1u);   // RTNE
  return (unsigned short)(u >> 16);
}

// ---------------- precomp1: T[513][4] = [Ws; bs] @ Wr ----------------
__global__ __launch_bounds__(256) void precomp1_kernel(
    const float* __restrict__ Ws, const float* __restrict__ bs,
    const float* __restrict__ Wr, float* __restrict__ T) {
  const int tid  = threadIdx.x;
  const int k    = blockIdx.x * 4 + (tid >> 6);   // wave id = output row
  const int lane = tid & 63;
  if (k >= 513) return;
  const float4* row4 = (const float4*)((k < 512) ? (Ws + (size_t)k * 4096) : bs);
  const float4* Wr4  = (const float4*)Wr;
  float a0 = 0.f, a1 = 0.f, a2 = 0.f, a3 = 0.f;
#pragma unroll 4
  for (int m4 = lane; m4 < 1024; m4 += 64) {
    const float4 rv = row4[m4];
#pragma unroll
    for (int c = 0; c < 4; ++c) {
      const float  xs = ((const float*)&rv)[c];
      const float4 w  = Wr4[m4 * 4 + c];
      a0 = fmaf(xs, w.x, a0); a1 = fmaf(xs, w.y, a1);
      a2 = fmaf(xs, w.z, a2); a3 = fmaf(xs, w.w, a3);
    }
  }
#pragma unroll
  for (int off = 32; off > 0; off >>= 1) {
    a0 += __shfl_xor(a0, off); a1 += __shfl_xor(a1, off);
    a2 += __shfl_xor(a2, off); a3 += __shfl_xor(a3, off);
  }
  if (lane == 0) {
    float4 o; o.x = a0; o.y = a1; o.z = a2; o.w = a3;
    ((float4*)T)[k] = o;
  }
}

// ---------------- precomp_small: blocks 0..32 -> WcBc; 33..40 -> Bfrag ----------------
__global__ __launch_bounds__(256) void precomp_small_kernel(
    const float* __restrict__ W1, const float* __restrict__ b1,
    const float* __restrict__ br, const float* __restrict__ T,
    float* __restrict__ WcBc,
    const float* __restrict__ W0, unsigned short* __restrict__ Bfrag) {
  if (blockIdx.x < 33) {
    const int i = blockIdx.x;        // 0..32 (32 -> b1 row)
    const int t = threadIdx.x;
    __shared__ float red[128];
    float acc = 0.f;
    if (t < 128) {
      const int j   = t & 3;
      const int seg = t >> 2;        // 0..31
      const float4* v4 = (const float4*)((i < 32) ? (W1 + (size_t)i * 512) : b1);
      const float4* T4 = (const float4*)T;
#pragma unroll
      for (int q = 0; q < 4; ++q) {
        const int m4 = seg * 4 + q;
        const float4 vv = v4[m4];
#pragma unroll
        for (int c = 0; c < 4; ++c) {
          const float4 trow = T4[m4 * 4 + c];
          acc = fmaf(((const float*)&vv)[c], ((const float*)&trow)[j], acc);
        }
      }
      red[t] = acc;
    }
    __syncthreads();
#pragma unroll
    for (int s = 64; s >= 4; s >>= 1) {
      if (t < s) red[t] += red[t + s];
      __syncthreads();
    }
    if (t < 4) {
      float r = red[t];
      if (i == 32) r += T[512 * 4 + t] + br[t];
      WcBc[(i < 32 ? i * 4 : 128) + t] = r;
    }
  } else {
    const int t  = (blockIdx.x - 33) * 256 + threadIdx.x;  // 0..2047
    const int f  = t >> 6;
    const int l  = t & 63;
    const int kk = f >> 1;
    const int nh = f & 1;
    const int n  = nh * 16 + (l & 15);
    unsigned int pk[4];
#pragma unroll
    for (int p = 0; p < 4; ++p) {
      const int k0 = kk * 32 + (l >> 4) * 8 + p * 2;
      const float v0 = (k0     < 484) ? W0[(size_t)k0 * 32 + n]       : 0.f;
      const float v1 = (k0 + 1 < 484) ? W0[(size_t)(k0 + 1) * 32 + n] : 0.f;
      pk[p] = (unsigned int)f2bf(v0) | ((unsigned int)f2bf(v1) << 16);
    }
    uint4 o; o.x = pk[0]; o.y = pk[1]; o.z = pk[2]; o.w = pk[3];
    ((uint4*)Bfrag)[t] = o;
  }
}

// ---------------- stage12: full fused pipeline per 64-row tile ----------------
// 512 blocks x 320 threads (5 waves). Block computes 68 y-rows (l0-4..l0+63,
// ring) via MFMA (M=80, rows 68..79 junk), folds through Wc into LDS, then
// the ring-5 relu layer + final projection for its 64 output rows.
__global__ __launch_bounds__(320) void stage12_kernel(
    const float* __restrict__ x, const unsigned short* __restrict__ Bfrag,
    const float* __restrict__ b0, const float* __restrict__ WcBc,
    const float* __restrict__ W2, const float* __restrict__ b2,
    const float* __restrict__ W3, const float* __restrict__ b3,
    float* __restrict__ out) {
  __shared__ unsigned short sX[NPOS * 4];  // [pos][ch] bf16, 1664 B
  __shared__ float sH[68][33];             // tanh outputs, padded
  __shared__ float sYv[68][4];             // y rows l0-4..l0+63
  __shared__ float sWc[132];               // Wc + bc
  __shared__ float sW2[20 * 32];           // relu-layer weights, 2560 B

  const int b    = blockIdx.x >> 6;        // 8 batches x 64 tiles
  const int tile = blockIdx.x & 63;
  const int l0   = tile * 64;
  const int tid  = threadIdx.x;

  // stage x window as bf16: pos p <-> x row (l0-124+p) mod L; p>=188 zero
  if (tid < NPOS) {
    float4 v = {0.f, 0.f, 0.f, 0.f};
    if (tid < 188)
      v = ((const float4*)(x + (size_t)b * L_SEQ * 4))[(l0 - 124 + tid) & (L_SEQ - 1)];
    ushort4 u;
    u.x = f2bf(v.x); u.y = f2bf(v.y); u.z = f2bf(v.z); u.w = f2bf(v.w);
    *(ushort4*)(sX + tid * 4) = u;
  }
  if (tid < 132) sWc[tid] = WcBc[tid];
  for (int i = tid; i < 640; i += 320) sW2[i] = W2[i];
  __syncthreads();

  const int lane = tid & 63;
  const int wid  = tid >> 6;               // 0..4 -> A-rows wid*16..+15
  const int rowb = wid * 16;

  // all 32 B-frags (same addresses across waves -> L1 broadcast)
  const bf16x8* Bf = (const bf16x8*)Bfrag;
  bf16x8 bw[32];
#pragma unroll
  for (int f = 0; f < 32; ++f) bw[f] = Bf[f * 64 + lane];

  const float bias0 = b0[lane & 15];
  const float bias1 = b0[16 + (lane & 15)];

  f32x4 acc0 = {0.f, 0.f, 0.f, 0.f};
  f32x4 acc1 = {0.f, 0.f, 0.f, 0.f};

#pragma unroll
  for (int kk = 0; kk < 16; ++kk) {
    // A-frag: lane l -> A-row rowb+(l&15), taps kk*8+2*(l>>4)+{0,1}, 4 ch each
    const int p0 = rowb + (lane & 15) + kk * 8 + 2 * (lane >> 4);
    union { uint4 u; bf16x8 v; } af;
    const uint2 lo = *(const uint2*)(sX + p0 * 4);
    const uint2 hi = *(const uint2*)(sX + p0 * 4 + 4);
    af.u.x = lo.x; af.u.y = lo.y; af.u.z = hi.x; af.u.w = hi.y;
    acc0 = __builtin_amdgcn_mfma_f32_16x16x32_bf16(af.v, bw[kk * 2 + 0], acc0, 0, 0, 0);
    acc1 = __builtin_amdgcn_mfma_f32_16x16x32_bf16(af.v, bw[kk * 2 + 1], acc1, 0, 0, 0);
  }

  // bias + tanh -> sH (C layout: col=lane&15, row=rowb+(lane>>4)*4+reg)
#pragma unroll
  for (int r = 0; r < 4; ++r) {
    const int row = rowb + (lane >> 4) * 4 + r;
    if (row < 68) {
      const float s0 = acc0[r] + bias0;
      const float s1 = acc1[r] + bias1;
      sH[row][lane & 15]        = 1.f - 2.f / (__expf(2.f * s0) + 1.f);
      sH[row][16 + (lane & 15)] = 1.f - 2.f / (__expf(2.f * s1) + 1.f);
    }
  }
  __syncthreads();

  // fold through Wc: y-row (l0-4+rr) -> sYv[rr]
  if (tid < 272) {
    const int rr = tid >> 2;
    const int j  = tid & 3;
    float o = sWc[128 + j];
#pragma unroll
    for (int n = 0; n < 32; ++n) o = fmaf(sH[rr][n], sWc[n * 4 + j], o);
    sYv[rr][j] = o;
  }
  __syncthreads();

  // ring-5 relu layer + projection. thread (rr, jg): neurons jg*8..+7 only;
  // partial o[4]; butterfly over the 4 jg-lanes (rr preserved); lane jg
  // writes component jg (coalesced).
  if (tid < 256) {
    const int rr = tid >> 2;
    const int jg = tid & 3;
    const int n0 = jg * 8;

    float4 w3r[8];                              // W3 rows n0..n0+7 (L1)
#pragma unroll
    for (int m = 0; m < 8; ++m) w3r[m] = ((const float4*)W3)[n0 + m];
    const float4 b2a = ((const float4*)b2)[jg * 2];
    const float4 b2b = ((const float4*)b2)[jg * 2 + 1];

    float win[20];
#pragma unroll
    for (int jj = 0; jj < 5; ++jj) {
      const float4 v = *(const float4*)&sYv[rr + jj][0];   // y row l0+rr-4+jj
      win[jj*4+0] = v.x; win[jj*4+1] = v.y; win[jj*4+2] = v.z; win[jj*4+3] = v.w;
    }

    float h[8] = {b2a.x, b2a.y, b2a.z, b2a.w, b2b.x, b2b.y, b2b.z, b2b.w};
#pragma unroll
    for (int k = 0; k < 20; ++k) {
      const float xs = win[k];
      const float4 wa = *(const float4*)&sW2[k * 32 + n0];      // banks disjoint per jg
      const float4 wb = *(const float4*)&sW2[k * 32 + n0 + 4];
      h[0] = fmaf(xs, wa.x, h[0]); h[1] = fmaf(xs, wa.y, h[1]);
      h[2] = fmaf(xs, wa.z, h[2]); h[3] = fmaf(xs, wa.w, h[3]);
      h[4] = fmaf(xs, wb.x, h[4]); h[5] = fmaf(xs, wb.y, h[5]);
      h[6] = fmaf(xs, wb.z, h[6]); h[7] = fmaf(xs, wb.w, h[7]);
    }

    float o0 = 0.f, o1 = 0.f, o2 = 0.f, o3 = 0.f;
#pragma unroll
    for (int m = 0; m < 8; ++m) {
      const float hv = fmaxf(h[m], 0.f);
      o0 = fmaf(hv, w3r[m].x, o0); o1 = fmaf(hv, w3r[m].y, o1);
      o2 = fmaf(hv, w3r[m].z, o2); o3 = fmaf(hv, w3r[m].w, o3);
    }
    o0 += __shfl_xor(o0, 1); o1 += __shfl_xor(o1, 1);
    o2 += __shfl_xor(o2, 1); o3 += __shfl_xor(o3, 1);
    o0 += __shfl_xor(o0, 2); o1 += __shfl_xor(o1, 2);
    o2 += __shfl_xor(o2, 2); o3 += __shfl_xor(o3, 2);
    const float ov = (jg == 0 ? o0 : jg == 1 ? o1 : jg == 2 ? o2 : o3) + b3[jg];
    out[((size_t)b * L_SEQ + l0 + rr) * 4 + jg] = ov;
  }
}

extern "C" void kernel_launch(void* const* d_in, const int* in_sizes, int n_in,
                              void* d_out, int out_size, void* d_ws, size_t ws_size,
                              hipStream_t stream) {
  const float* x  = (const float*)d_in[0];   // [8,4096,4]
  const float* W0 = (const float*)d_in[1];   // [484,32]
  const float* b0 = (const float*)d_in[2];   // [32]
  const float* W1 = (const float*)d_in[3];   // [32,512]
  const float* b1 = (const float*)d_in[4];   // [512]
  const float* Ws = (const float*)d_in[5];   // [512,4096]
  const float* bs = (const float*)d_in[6];   // [4096]
  const float* Wr = (const float*)d_in[7];   // [4096,4]
  const float* br = (const float*)d_in[8];   // [4]
  const float* W2 = (const float*)d_in[9];   // [20,32]
  const float* b2 = (const float*)d_in[10];  // [32]
  const float* W3 = (const float*)d_in[11];  // [32,4]
  const float* b3 = (const float*)d_in[12];  // [4]
  float* outp = (float*)d_out;               // [8,4096,4]

  // ws (floats): T[2052] @0, WcBc[132] @2052, Bfrag (16384 ushort) @2304
  float* T    = (float*)d_ws;
  float* WcBc = T + 2052;
  unsigned short* Bfrag = (unsigned short*)((float*)d_ws + 2304);

  precomp1_kernel<<<129, 256, 0, stream>>>(Ws, bs, Wr, T);
  precomp_small_kernel<<<41, 256, 0, stream>>>(W1, b1, br, T, WcBc, W0, Bfrag);
  stage12_kernel<<<512, 320, 0, stream>>>(x, Bfrag, b0, WcBc, W2, b2, W3, b3, outp);
}